// Round 14
// baseline (190.965 us; speedup 1.0000x reference)
//
#include <hip/hip_runtime.h>

typedef _Float16 f16;
typedef __fp16 fp16x2 __attribute__((ext_vector_type(2)));
typedef _Float16 f16x8 __attribute__((ext_vector_type(8)));
typedef float f32x4 __attribute__((ext_vector_type(4)));
typedef float f32x16 __attribute__((ext_vector_type(16)));

#define AS1 __attribute__((address_space(1)))
#define AS3 __attribute__((address_space(3)))

#define SCALE_L2E 0.18033688011112042f   // 0.125 * log2(e), folded into Q

// ---- helpers ---------------------------------------------------------------

__device__ __forceinline__ void gload16(const void* g, void* l) {
    __builtin_amdgcn_global_load_lds(
        (const AS1 unsigned*)(unsigned long long)g,
        (AS3 unsigned*)(unsigned)(unsigned long long)l,
        16, 0, 0);
}

__device__ __forceinline__ unsigned pk2(float a, float b) {
    union { fp16x2 v; unsigned u; } c;
    c.v = __builtin_amdgcn_cvt_pkrtz(a, b);
    return c.u;
}

#define BAR() do { asm volatile("" ::: "memory"); __builtin_amdgcn_s_barrier(); asm volatile("" ::: "memory"); } while (0)

// ---- fused fp32 -> fp16 casts + RoPE table (one launch) ---------------------

__global__ __launch_bounds__(256) void k_cast_all(const float* __restrict__ x,
                                                  const float* __restrict__ wq,
                                                  const float* __restrict__ wo,
                                                  f16* __restrict__ Xh,
                                                  f16* __restrict__ Wqh,
                                                  f16* __restrict__ Woh,
                                                  float* __restrict__ cosT,
                                                  float* __restrict__ sinT) {
    if (blockIdx.x >= 18432) {   // RoPE table: 256 blocks x 256 thr = 65536
        int idx = (blockIdx.x - 18432) * 256 + threadIdx.x;
        int s = idx >> 5, i = idx & 31;
        float ang = (float)s * exp2f(-(float)i * 0.4152410118609190f);
        cosT[idx] = cosf(ang);
        sinT[idx] = sinf(ang);
        return;
    }
    int i = (blockIdx.x * 256 + threadIdx.x) * 4;
    const float* src; f16* dst;
    if (i < 8388608)        { src = x  + i;            dst = Xh  + i; }
    else if (i < 14680064)  { src = wq + (i - 8388608); dst = Wqh + (i - 8388608); }
    else                    { src = wo + (i - 14680064); dst = Woh + (i - 14680064); }
    float4 v = *(const float4*)src;
    union { f16 h[4]; ushort4 u; } c;
    c.h[0] = (f16)v.x; c.h[1] = (f16)v.y; c.h[2] = (f16)v.z; c.h[3] = (f16)v.w;
    *(ushort4*)dst = c.u;
}

// ---- GEMM, 256 x (64*NU) tile, 8-phase counted-vmcnt schedule --------------

template <typename OutT, int NU>
__global__ __launch_bounds__(512, 2) void k_gemm256(const f16* __restrict__ A,
                                                    const f16* __restrict__ Bt,
                                                    OutT* __restrict__ C,
                                                    int M, int N, int K) {
    constexpr int BUFSZ = 32768 + NU * 8192;
    __shared__ __align__(16) char sm[2 * BUFSZ];
    const int tid = threadIdx.x;
    const int lane = tid & 63, wid = tid >> 6;
    const int wm = wid >> 2, wn = wid & 3;          // 2 x 4 waves
    const int lr = lane & 15, g4 = lane >> 4;

    // XCD-aware swizzle (bijective: nwg % 8 == 0 for all our grids)
    const int gx = gridDim.x;
    const int nwg = gx * gridDim.y;
    int lin = blockIdx.y * gx + blockIdx.x;
    lin = (lin & 7) * (nwg >> 3) + (lin >> 3);
    const int bx = lin % gx, by = lin / gx;
    const int m0 = by * 256, n0 = bx * (64 * NU);
    const int NT = K >> 6;

    const int srow = tid >> 3;                          // 0..63
    const int scol = ((tid & 7) ^ (srow & 7)) * 8;      // halfs (pre-swizzled)
    const f16* gA = A  + (size_t)(m0 + srow) * K + scol;
    const f16* gB = Bt + (size_t)(n0 + srow) * K + scol;

    auto STGA = [&](int t, int h) {
        char* d = sm + (t & 1) * BUFSZ + h * 16384 + tid * 16;
        gload16(gA + (size_t)(h * 128) * K + t * 64,      d);
        gload16(gA + (size_t)(h * 128 + 64) * K + t * 64, d + 8192);
    };
    auto STGB = [&](int t) {
#pragma unroll
        for (int u = 0; u < NU; u++)
            gload16(gB + (size_t)(u * 64) * K + t * 64,
                    sm + (t & 1) * BUFSZ + 32768 + u * 8192 + tid * 16);
    };

    f32x4 acc[8][NU] = {};
    f16x8 bfr[NU];

    STGA(0, 0); STGA(0, 1); STGB(0);
    STGA(1, 0); STGA(1, 1); STGB(1);
    if constexpr (NU == 2) asm volatile("s_waitcnt vmcnt(6)" ::: "memory");
    else                   asm volatile("s_waitcnt vmcnt(7)" ::: "memory");
    BAR();

    for (int t = 0; t < NT; ++t) {
        const int buf = t & 1;
        const char* bA = sm + buf * BUFSZ + wm * 16384;
        const char* bB = sm + buf * BUFSZ + 32768;
        const bool sA = (t >= 1) && (t + 1 < NT);
        const bool sB = (t + 2 < NT);
#pragma unroll
        for (int p = 0; p < 4; ++p) {
            const int kk = p >> 1, mh = p & 1;
            f16x8 afr[4];
            if (mh == 0) {
#pragma unroll
                for (int n = 0; n < NU; n++) {
                    const int r = wn * (16 * NU) + n * 16 + lr;
                    bfr[n] = *(const f16x8*)(bB + ((r * 128 + kk * 64 + g4 * 16) ^ ((r & 7) << 4)));
                }
            }
#pragma unroll
            for (int i = 0; i < 4; i++) {
                const int r = (mh * 4 + i) * 16 + lr;
                afr[i] = *(const f16x8*)(bA + ((r * 128 + kk * 64 + g4 * 16) ^ ((r & 7) << 4)));
            }
            if (p == 0 && sA) STGA(t + 1, 0);
            if (p == 1 && sA) STGA(t + 1, 1);
            if (p == 3 && sB) STGB(t + 2);
            BAR();
            asm volatile("s_waitcnt lgkmcnt(0)" ::: "memory");
            __builtin_amdgcn_s_setprio(1);
#pragma unroll
            for (int i = 0; i < 4; i++)
#pragma unroll
                for (int n = 0; n < NU; n++)
                    acc[mh * 4 + i][n] = __builtin_amdgcn_mfma_f32_16x16x32_f16(afr[i], bfr[n], acc[mh * 4 + i][n], 0, 0, 0);
            __builtin_amdgcn_s_setprio(0);
            if (p == 3 && t + 1 < NT) {
                if (t + 2 < NT) {
                    if constexpr (NU == 2) asm volatile("s_waitcnt vmcnt(2)" ::: "memory");
                    else                   asm volatile("s_waitcnt vmcnt(3)" ::: "memory");
                } else {
                    asm volatile("s_waitcnt vmcnt(0)" ::: "memory");
                }
            }
            BAR();
        }
    }

#pragma unroll
    for (int m = 0; m < 8; m++)
#pragma unroll
        for (int n = 0; n < NU; n++) {
            size_t base = (size_t)(m0 + wm * 128 + m * 16 + g4 * 4) * N + (n0 + wn * (16 * NU) + n * 16 + lr);
#pragma unroll
            for (int j = 0; j < 4; j++)
                C[base + (size_t)j * N] = (OutT)acc[m][n][j];
        }
}

// ---- fused RMSNorm + RoPE + QKV split, FRAGMENT-MAJOR outputs ---------------

__global__ __launch_bounds__(256) void k_qkv_post(const f16* __restrict__ qkv,
                                                  const float* __restrict__ qg,
                                                  const float* __restrict__ kg,
                                                  const float* __restrict__ cosT,
                                                  const float* __restrict__ sinT,
                                                  f16* __restrict__ Qf,
                                                  f16* __restrict__ Kf,
                                                  f16* __restrict__ Vf) {
    __shared__ f16 tl[4][8][72];         // per-wave 8x64 transpose tile (V path)
    const int tid = threadIdx.x, lane = tid & 63, wv = tid >> 6;
    const int gw = blockIdx.x * 4 + wv;             // 0..24575
    const int b = gw / 12288;
    const int r0 = gw - b * 12288;
    const int head = r0 >> 8;                        // 0..47
    const int sblk = r0 & 255;
    const int s0 = sblk * 8;
    const int s_loc = lane >> 3, ch = lane & 7;
    const int s = s0 + s_loc;

    f16x8 v = *(const f16x8*)&qkv[((size_t)b * 2048 + s) * 3072 + head * 64 + ch * 8];

    if (head < 40) {
        float vf[8];
#pragma unroll
        for (int j = 0; j < 8; j++) vf[j] = (float)v[j];
        float ss = 0.f;
#pragma unroll
        for (int j = 0; j < 8; j++) ss += vf[j] * vf[j];
        ss += __shfl_xor(ss, 1); ss += __shfl_xor(ss, 2); ss += __shfl_xor(ss, 4);
        float rinv = rsqrtf(ss * (1.0f / 64.0f) + 1e-6f);
        const float* gam = (head < 32 ? qg : kg) + ch * 8;
        float4 g0 = *(const float4*)gam, g1 = *(const float4*)(gam + 4);
        float gv[8] = {g0.x, g0.y, g0.z, g0.w, g1.x, g1.y, g1.z, g1.w};
        float xn[8], ot[8];
#pragma unroll
        for (int j = 0; j < 8; j++) xn[j] = vf[j] * rinv * gv[j];
#pragma unroll
        for (int j = 0; j < 8; j++) ot[j] = __shfl_xor(xn[j], 4);
        const int i0 = (ch & 3) * 8;
        float4 c0  = *(const float4*)&cosT[(s << 5) + i0];
        float4 c1  = *(const float4*)&cosT[(s << 5) + i0 + 4];
        float4 sn0 = *(const float4*)&sinT[(s << 5) + i0];
        float4 sn1 = *(const float4*)&sinT[(s << 5) + i0 + 4];
        float cs[8] = {c0.x, c0.y, c0.z, c0.w, c1.x, c1.y, c1.z, c1.w};
        float sn[8] = {sn0.x, sn0.y, sn0.z, sn0.w, sn1.x, sn1.y, sn1.z, sn1.w};
        float sgn = (ch < 4) ? -1.0f : 1.0f;
        float ov[8];
#pragma unroll
        for (int j = 0; j < 8; j++) ov[j] = xn[j] * cs[j] + sgn * ot[j] * sn[j];
        if (head < 32) {
#pragma unroll
            for (int j = 0; j < 8; j++) ov[j] *= SCALE_L2E;
        }
        uint4 o;
        o.x = pk2(ov[0], ov[1]); o.y = pk2(ov[2], ov[3]);
        o.z = pk2(ov[4], ov[5]); o.w = pk2(ov[6], ov[7]);
        const int t = s >> 5;
        const int lane2 = (s & 31) + ((ch & 1) << 5);
        const int c = ch >> 1;
        f16* dst = (head < 32)
            ? Qf + (((size_t)(b * 32 + head) * 256 + t * 4 + c) * 512 + lane2 * 8)
            : Kf + (((size_t)(b * 8 + head - 32) * 256 + t * 4 + c) * 512 + lane2 * 8);
        *(uint4*)dst = o;
    } else {
        const int kh = head - 40;
        *(f16x8*)&tl[wv][s_loc][ch * 8] = v;
        asm volatile("s_waitcnt lgkmcnt(0)" ::: "memory");
        f16x8 cv;
#pragma unroll
        for (int rr = 0; rr < 8; rr++) cv[rr] = tl[wv][rr][lane];
        const int d = lane, dh = d >> 5;
        const int t = s0 >> 5, c = (s0 >> 4) & 1, hv = (s0 >> 3) & 1;
        const int g = dh * 2 + c;
        f16* dst = Vf + (((size_t)(b * 8 + kh) * 256 + t * 4 + g) * 512
                         + ((d & 31) + (hv << 5)) * 8);
        *(f16x8*)dst = cv;
    }
}

// ---- flash attention, causal, GQA, split-KV x2, 2-tile pipelined ------------
// R10 structure (best measured), no setprio, POINTER-BUMP addressing:
// K/V bases computed once per session, advanced by constant element strides;
// intra-tile fragment offsets are compile-time immediates (offset:0..3072B).

struct AttnPart { f32x16 o0, o1; float l; };

__device__ __forceinline__ void do_exp(const f32x16& st, unsigned* X, float& lrun) {
    float ps0 = 0.0f, ps1 = 0.0f;
#pragma unroll
    for (int j = 0; j < 8; j++) {
        float p0 = __builtin_amdgcn_exp2f(st[2 * j]);
        float p1 = __builtin_amdgcn_exp2f(st[2 * j + 1]);
        ps0 += p0; ps1 += p1;
        X[j] = pk2(p0, p1);
    }
    lrun += ps0 + ps1;
}

__device__ __forceinline__ void do_pv(const f16x8* va, const f16x8* vb,
                                      const unsigned* X, f32x16& o0, f32x16& o1) {
#pragma unroll
    for (int c = 0; c < 2; c++) {
        unsigned a0 = X[4 * c], a1 = X[4 * c + 1], a2 = X[4 * c + 2], a3 = X[4 * c + 3];
        asm volatile("v_permlane32_swap_b32 %0, %1" : "+v"(a0), "+v"(a2));
        asm volatile("v_permlane32_swap_b32 %0, %1" : "+v"(a1), "+v"(a3));
        union { unsigned u[4]; f16x8 v; } pb;
        pb.u[0] = a0; pb.u[1] = a1; pb.u[2] = a2; pb.u[3] = a3;
        o0 = __builtin_amdgcn_mfma_f32_32x32x16_f16(va[c], pb.v, o0, 0, 0, 0);
        o1 = __builtin_amdgcn_mfma_f32_32x32x16_f16(vb[c], pb.v, o1, 0, 0, 0);
    }
}

__device__ __forceinline__ void do_mask(f32x16& st, int lq, int hi) {
#pragma unroll
    for (int r = 0; r < 16; r++) {
        int kvl = (r & 3) + ((r >> 2) << 3) + (hi << 2);
        if (kvl > lq) st[r] = -1e30f;
    }
}

__device__ __forceinline__ f32x16 qk_mfma(const f16x8* kf, const f16x8* qf) {
    f32x16 st = {};
#pragma unroll
    for (int c = 0; c < 4; c++)
        st = __builtin_amdgcn_mfma_f32_32x32x16_f16(kf[c], qf[c], st, 0, 0, 0);
    return st;
}

__device__ __forceinline__ void LOADKp(f16x8* kf, const f16* p) {
#pragma unroll
    for (int c = 0; c < 4; c++) kf[c] = *(const f16x8*)(p + c * 512);
}
__device__ __forceinline__ void LOADVp(f16x8* va, f16x8* vb, const f16* p) {
#pragma unroll
    for (int c = 0; c < 2; c++) {
        va[c] = *(const f16x8*)(p + c * 512);
        vb[c] = *(const f16x8*)(p + (2 + c) * 512);
    }
}

__device__ __forceinline__ AttnPart attn_part(int qb, int par, int lane, int lq, int hi,
        const f16* __restrict__ Qfp, const f16* __restrict__ Kfp,
        const f16* __restrict__ Vfp) {
    f16x8 qf[4];
#pragma unroll
    for (int c = 0; c < 4; c++)
        qf[c] = *(const f16x8*)&Qfp[((size_t)qb * 4 + c) * 512 + lane * 8];

    AttnPart P;
    P.o0 = (f32x16){}; P.o1 = (f32x16){};
    float lrun = 0.0f;

    f16x8 kfa[4], kfb[4], vaa[2], vba[2], vab[2], vbb[2];

    // pointer-bump bases: tile t lives at base + t*2048 elements
    const f16* kpa = Kfp + par * 2048 + lane * 8;
    const f16* vpa = Vfp + par * 2048 + lane * 8;
    const f16* kpb = kpa + 2 * 2048;
    const f16* vpb = vpa + 2 * 2048;

    int kt = par;
    if (kt <= qb)     { LOADKp(kfa, kpa); LOADVp(vaa, vba, vpa); }
    if (kt + 2 <= qb) { LOADKp(kfb, kpb); LOADVp(vab, vbb, vpb); }

    while (kt + 2 <= qb) {
        const int nx = kt + 4;
        f32x16 sta = qk_mfma(kfa, qf);
        unsigned Xa[8];
        do_exp(sta, Xa, lrun);                       // tile a is never diagonal

        f32x16 stb = qk_mfma(kfb, qf);
        if (nx <= qb) { kpa += 4 * 2048; LOADKp(kfa, kpa); }

        do_pv(vaa, vba, Xa, P.o0, P.o1);
        if (nx <= qb) { vpa += 4 * 2048; LOADVp(vaa, vba, vpa); }

        if (kt + 2 == qb) do_mask(stb, lq, hi);
        unsigned Xb[8];
        do_exp(stb, Xb, lrun);
        if (nx + 2 <= qb) { kpb += 4 * 2048; LOADKp(kfb, kpb); }

        do_pv(vab, vbb, Xb, P.o0, P.o1);
        if (nx + 2 <= qb) { vpb += 4 * 2048; LOADVp(vab, vbb, vpb); }

        kt = nx;
    }
    if (kt <= qb) {          // leftover single tile (possibly diagonal)
        f32x16 st = qk_mfma(kfa, qf);
        if (kt == qb) do_mask(st, lq, hi);
        unsigned X[8];
        do_exp(st, X, lrun);
        do_pv(vaa, vba, X, P.o0, P.o1);
    }

    P.l = lrun + __shfl_xor(lrun, 32);
    return P;
}

__global__ __launch_bounds__(128) void k_attn(const f16* __restrict__ Qf,
                                              const f16* __restrict__ Kf,
                                              const f16* __restrict__ Vf,
                                              f16* __restrict__ ctx) {
    __shared__ float ldsO[32][65];
    __shared__ float ldsL[32];
    const int tid = threadIdx.x;
    const int par = tid >> 6, lane = tid & 63;
    const int lq = lane & 31, hi = lane >> 5;
    const int bh = blockIdx.y, b = bh >> 5, h = bh & 31, kh = h >> 2;
    const int pj = blockIdx.x;                    // 0..31

    const f16* Qfp = Qf + (size_t)(b * 32 + h) * 131072;
    const f16* Kfp = Kf + (size_t)(b * 8 + kh) * 131072;
    const f16* Vfp = Vf + (size_t)(b * 8 + kh) * 131072;
    f16*       ctxbase = ctx + (size_t)b * 2048 * 2048 + h * 64;

    const int qbs[2] = {pj, 63 - pj};
#pragma unroll
    for (int s = 0; s < 2; s++) {
        const int qb = qbs[s];
        AttnPart P = attn_part(qb, par, lane, lq, hi, Qfp, Kfp, Vfp);

        if (par == 1) {
            if (hi == 0) ldsL[lq] = P.l;
#pragma unroll
            for (int r = 0; r < 16; r++) {
                int d = (r & 3) + ((r >> 2) << 3) + (hi << 2);
                ldsO[lq][d]      = P.o0[r];
                ldsO[lq][d + 32] = P.o1[r];
            }
        }
        __syncthreads();
        if (par == 0) {
            float inv = 1.0f / (P.l + ldsL[lq]);
            unsigned* row = (unsigned*)(ctxbase + (size_t)(qb * 32 + lq) * 2048);
#pragma unroll
            for (int g = 0; g < 4; g++) {
                int d = 8 * g + 4 * hi;
                float c0 = (P.o0[4 * g]     + ldsO[lq][d])     * inv;
                float c1 = (P.o0[4 * g + 1] + ldsO[lq][d + 1]) * inv;
                float c2 = (P.o0[4 * g + 2] + ldsO[lq][d + 2]) * inv;
                float c3 = (P.o0[4 * g + 3] + ldsO[lq][d + 3]) * inv;
                uint2 a; a.x = pk2(c0, c1); a.y = pk2(c2, c3);
                *(uint2*)(row + 2 * hi + 4 * g) = a;
                float e0 = (P.o1[4 * g]     + ldsO[lq][d + 32]) * inv;
                float e1 = (P.o1[4 * g + 1] + ldsO[lq][d + 33]) * inv;
                float e2 = (P.o1[4 * g + 2] + ldsO[lq][d + 34]) * inv;
                float e3 = (P.o1[4 * g + 3] + ldsO[lq][d + 35]) * inv;
                uint2 e; e.x = pk2(e0, e1); e.y = pk2(e2, e3);
                *(uint2*)(row + 16 + 2 * hi + 4 * g) = e;
            }
        }
        __syncthreads();
    }
}

// ---- launcher ---------------------------------------------------------------

extern "C" void kernel_launch(void* const* d_in, const int* in_sizes, int n_in,
                              void* d_out, int out_size, void* d_ws, size_t ws_size,
                              hipStream_t stream) {
    const float* x     = (const float*)d_in[0];
    const float* w_qkv = (const float*)d_in[1];
    const float* w_out = (const float*)d_in[2];
    const float* qg    = (const float*)d_in[3];
    const float* kg    = (const float*)d_in[4];
    float* out = (float*)d_out;
    char* ws = (char*)d_ws;

    float* cosT = (float*)(ws);
    float* sinT = (float*)(ws + 262144);
    f16* Xh     = (f16*)(ws + 524288);
    f16* Wqkvh  = (f16*)(ws + 17301504);
    f16* Wouth  = (f16*)(ws + 29884416);
    f16* QKVh   = (f16*)(ws + 38273024);
    f16* Qfb    = (f16*)(ws + 63438848);    // fragment-major Q (pre-scaled), 16 MB
    f16* Kfb    = (f16*)(ws + 80216064);    // fragment-major K, 4 MB
    f16* Vfb    = (f16*)(ws + 84410368);    // fragment-major V, 4 MB
    f16* Ctxh   = (f16*)(ws + 88604672);

    k_cast_all<<<18688, 256, 0, stream>>>(x, w_qkv, w_out, Xh, Wqkvh, Wouth, cosT, sinT);

    // qkv = x @ w_qkv^T : M=4096, N=3072, K=2048  (256x192 tile, 256 blocks)
    k_gemm256<f16, 3><<<dim3(16, 16), 512, 0, stream>>>(Xh, Wqkvh, QKVh, 4096, 3072, 2048);

    // fragment-major post-process: 24576 waves / 4 per block
    k_qkv_post<<<6144, 256, 0, stream>>>(QKVh, qg, kg, cosT, sinT, Qfb, Kfb, Vfb);

    // attention: 2048 blocks x 1 wave-pair, split-KV x2, 2-tile pipelined
    k_attn<<<dim3(32, 64), 128, 0, stream>>>(Qfb, Kfb, Vfb, Ctxh);

    // out = ctx @ w_out^T : M=4096, N=2048, K=2048  (256x128 tile, 256 blocks)
    k_gemm256<float, 2><<<dim3(16, 16), 512, 0, stream>>>(Ctxh, Wouth, out, 4096, 2048, 2048);
}

// Round 15
// 187.598 us; speedup vs baseline: 1.0179x; 1.0179x over previous
//
#include <hip/hip_runtime.h>

typedef _Float16 f16;
typedef __fp16 fp16x2 __attribute__((ext_vector_type(2)));
typedef _Float16 f16x8 __attribute__((ext_vector_type(8)));
typedef float f32x4 __attribute__((ext_vector_type(4)));
typedef float f32x16 __attribute__((ext_vector_type(16)));

#define AS1 __attribute__((address_space(1)))
#define AS3 __attribute__((address_space(3)))

#define SCALE_L2E 0.18033688011112042f   // 0.125 * log2(e), folded into Q

// ---- helpers ---------------------------------------------------------------

__device__ __forceinline__ void gload16(const void* g, void* l) {
    __builtin_amdgcn_global_load_lds(
        (const AS1 unsigned*)(unsigned long long)g,
        (AS3 unsigned*)(unsigned)(unsigned long long)l,
        16, 0, 0);
}

__device__ __forceinline__ unsigned pk2(float a, float b) {
    union { fp16x2 v; unsigned u; } c;
    c.v = __builtin_amdgcn_cvt_pkrtz(a, b);
    return c.u;
}

#define BAR() do { asm volatile("" ::: "memory"); __builtin_amdgcn_s_barrier(); asm volatile("" ::: "memory"); } while (0)

// ---- fused fp32 -> fp16 casts + RoPE table (one launch) ---------------------

__global__ __launch_bounds__(256) void k_cast_all(const float* __restrict__ x,
                                                  const float* __restrict__ wq,
                                                  const float* __restrict__ wo,
                                                  f16* __restrict__ Xh,
                                                  f16* __restrict__ Wqh,
                                                  f16* __restrict__ Woh,
                                                  float* __restrict__ cosT,
                                                  float* __restrict__ sinT) {
    if (blockIdx.x >= 18432) {   // RoPE table: 256 blocks x 256 thr = 65536
        int idx = (blockIdx.x - 18432) * 256 + threadIdx.x;
        int s = idx >> 5, i = idx & 31;
        float ang = (float)s * exp2f(-(float)i * 0.4152410118609190f);
        cosT[idx] = cosf(ang);
        sinT[idx] = sinf(ang);
        return;
    }
    int i = (blockIdx.x * 256 + threadIdx.x) * 4;
    const float* src; f16* dst;
    if (i < 8388608)        { src = x  + i;            dst = Xh  + i; }
    else if (i < 14680064)  { src = wq + (i - 8388608); dst = Wqh + (i - 8388608); }
    else                    { src = wo + (i - 14680064); dst = Woh + (i - 14680064); }
    float4 v = *(const float4*)src;
    union { f16 h[4]; ushort4 u; } c;
    c.h[0] = (f16)v.x; c.h[1] = (f16)v.y; c.h[2] = (f16)v.z; c.h[3] = (f16)v.w;
    *(ushort4*)dst = c.u;
}

// ---- GEMM, 256 x (64*NU) tile, 8-phase counted-vmcnt schedule --------------

template <typename OutT, int NU>
__global__ __launch_bounds__(512, 2) void k_gemm256(const f16* __restrict__ A,
                                                    const f16* __restrict__ Bt,
                                                    OutT* __restrict__ C,
                                                    int M, int N, int K) {
    constexpr int BUFSZ = 32768 + NU * 8192;
    __shared__ __align__(16) char sm[2 * BUFSZ];
    const int tid = threadIdx.x;
    const int lane = tid & 63, wid = tid >> 6;
    const int wm = wid >> 2, wn = wid & 3;          // 2 x 4 waves
    const int lr = lane & 15, g4 = lane >> 4;

    // XCD-aware swizzle (bijective: nwg % 8 == 0 for all our grids)
    const int gx = gridDim.x;
    const int nwg = gx * gridDim.y;
    int lin = blockIdx.y * gx + blockIdx.x;
    lin = (lin & 7) * (nwg >> 3) + (lin >> 3);
    const int bx = lin % gx, by = lin / gx;
    const int m0 = by * 256, n0 = bx * (64 * NU);
    const int NT = K >> 6;

    const int srow = tid >> 3;                          // 0..63
    const int scol = ((tid & 7) ^ (srow & 7)) * 8;      // halfs (pre-swizzled)
    const f16* gA = A  + (size_t)(m0 + srow) * K + scol;
    const f16* gB = Bt + (size_t)(n0 + srow) * K + scol;

    auto STGA = [&](int t, int h) {
        char* d = sm + (t & 1) * BUFSZ + h * 16384 + tid * 16;
        gload16(gA + (size_t)(h * 128) * K + t * 64,      d);
        gload16(gA + (size_t)(h * 128 + 64) * K + t * 64, d + 8192);
    };
    auto STGB = [&](int t) {
#pragma unroll
        for (int u = 0; u < NU; u++)
            gload16(gB + (size_t)(u * 64) * K + t * 64,
                    sm + (t & 1) * BUFSZ + 32768 + u * 8192 + tid * 16);
    };

    f32x4 acc[8][NU] = {};
    f16x8 bfr[NU];

    STGA(0, 0); STGA(0, 1); STGB(0);
    STGA(1, 0); STGA(1, 1); STGB(1);
    if constexpr (NU == 2) asm volatile("s_waitcnt vmcnt(6)" ::: "memory");
    else                   asm volatile("s_waitcnt vmcnt(7)" ::: "memory");
    BAR();

    for (int t = 0; t < NT; ++t) {
        const int buf = t & 1;
        const char* bA = sm + buf * BUFSZ + wm * 16384;
        const char* bB = sm + buf * BUFSZ + 32768;
        const bool sA = (t >= 1) && (t + 1 < NT);
        const bool sB = (t + 2 < NT);
#pragma unroll
        for (int p = 0; p < 4; ++p) {
            const int kk = p >> 1, mh = p & 1;
            f16x8 afr[4];
            if (mh == 0) {
#pragma unroll
                for (int n = 0; n < NU; n++) {
                    const int r = wn * (16 * NU) + n * 16 + lr;
                    bfr[n] = *(const f16x8*)(bB + ((r * 128 + kk * 64 + g4 * 16) ^ ((r & 7) << 4)));
                }
            }
#pragma unroll
            for (int i = 0; i < 4; i++) {
                const int r = (mh * 4 + i) * 16 + lr;
                afr[i] = *(const f16x8*)(bA + ((r * 128 + kk * 64 + g4 * 16) ^ ((r & 7) << 4)));
            }
            if (p == 0 && sA) STGA(t + 1, 0);
            if (p == 1 && sA) STGA(t + 1, 1);
            if (p == 3 && sB) STGB(t + 2);
            BAR();
            asm volatile("s_waitcnt lgkmcnt(0)" ::: "memory");
            __builtin_amdgcn_s_setprio(1);
#pragma unroll
            for (int i = 0; i < 4; i++)
#pragma unroll
                for (int n = 0; n < NU; n++)
                    acc[mh * 4 + i][n] = __builtin_amdgcn_mfma_f32_16x16x32_f16(afr[i], bfr[n], acc[mh * 4 + i][n], 0, 0, 0);
            __builtin_amdgcn_s_setprio(0);
            if (p == 3 && t + 1 < NT) {
                if (t + 2 < NT) {
                    if constexpr (NU == 2) asm volatile("s_waitcnt vmcnt(2)" ::: "memory");
                    else                   asm volatile("s_waitcnt vmcnt(3)" ::: "memory");
                } else {
                    asm volatile("s_waitcnt vmcnt(0)" ::: "memory");
                }
            }
            BAR();
        }
    }

#pragma unroll
    for (int m = 0; m < 8; m++)
#pragma unroll
        for (int n = 0; n < NU; n++) {
            size_t base = (size_t)(m0 + wm * 128 + m * 16 + g4 * 4) * N + (n0 + wn * (16 * NU) + n * 16 + lr);
#pragma unroll
            for (int j = 0; j < 4; j++)
                C[base + (size_t)j * N] = (OutT)acc[m][n][j];
        }
}

// ---- fused RMSNorm + RoPE + QKV split, FRAGMENT-MAJOR outputs ---------------

__global__ __launch_bounds__(256) void k_qkv_post(const f16* __restrict__ qkv,
                                                  const float* __restrict__ qg,
                                                  const float* __restrict__ kg,
                                                  const float* __restrict__ cosT,
                                                  const float* __restrict__ sinT,
                                                  f16* __restrict__ Qf,
                                                  f16* __restrict__ Kf,
                                                  f16* __restrict__ Vf) {
    __shared__ f16 tl[4][8][72];         // per-wave 8x64 transpose tile (V path)
    const int tid = threadIdx.x, lane = tid & 63, wv = tid >> 6;
    const int gw = blockIdx.x * 4 + wv;             // 0..24575
    const int b = gw / 12288;
    const int r0 = gw - b * 12288;
    const int head = r0 >> 8;                        // 0..47
    const int sblk = r0 & 255;
    const int s0 = sblk * 8;
    const int s_loc = lane >> 3, ch = lane & 7;
    const int s = s0 + s_loc;

    f16x8 v = *(const f16x8*)&qkv[((size_t)b * 2048 + s) * 3072 + head * 64 + ch * 8];

    if (head < 40) {
        float vf[8];
#pragma unroll
        for (int j = 0; j < 8; j++) vf[j] = (float)v[j];
        float ss = 0.f;
#pragma unroll
        for (int j = 0; j < 8; j++) ss += vf[j] * vf[j];
        ss += __shfl_xor(ss, 1); ss += __shfl_xor(ss, 2); ss += __shfl_xor(ss, 4);
        float rinv = rsqrtf(ss * (1.0f / 64.0f) + 1e-6f);
        const float* gam = (head < 32 ? qg : kg) + ch * 8;
        float4 g0 = *(const float4*)gam, g1 = *(const float4*)(gam + 4);
        float gv[8] = {g0.x, g0.y, g0.z, g0.w, g1.x, g1.y, g1.z, g1.w};
        float xn[8], ot[8];
#pragma unroll
        for (int j = 0; j < 8; j++) xn[j] = vf[j] * rinv * gv[j];
#pragma unroll
        for (int j = 0; j < 8; j++) ot[j] = __shfl_xor(xn[j], 4);
        const int i0 = (ch & 3) * 8;
        float4 c0  = *(const float4*)&cosT[(s << 5) + i0];
        float4 c1  = *(const float4*)&cosT[(s << 5) + i0 + 4];
        float4 sn0 = *(const float4*)&sinT[(s << 5) + i0];
        float4 sn1 = *(const float4*)&sinT[(s << 5) + i0 + 4];
        float cs[8] = {c0.x, c0.y, c0.z, c0.w, c1.x, c1.y, c1.z, c1.w};
        float sn[8] = {sn0.x, sn0.y, sn0.z, sn0.w, sn1.x, sn1.y, sn1.z, sn1.w};
        float sgn = (ch < 4) ? -1.0f : 1.0f;
        float ov[8];
#pragma unroll
        for (int j = 0; j < 8; j++) ov[j] = xn[j] * cs[j] + sgn * ot[j] * sn[j];
        if (head < 32) {
#pragma unroll
            for (int j = 0; j < 8; j++) ov[j] *= SCALE_L2E;
        }
        uint4 o;
        o.x = pk2(ov[0], ov[1]); o.y = pk2(ov[2], ov[3]);
        o.z = pk2(ov[4], ov[5]); o.w = pk2(ov[6], ov[7]);
        const int t = s >> 5;
        const int lane2 = (s & 31) + ((ch & 1) << 5);
        const int c = ch >> 1;
        f16* dst = (head < 32)
            ? Qf + (((size_t)(b * 32 + head) * 256 + t * 4 + c) * 512 + lane2 * 8)
            : Kf + (((size_t)(b * 8 + head - 32) * 256 + t * 4 + c) * 512 + lane2 * 8);
        *(uint4*)dst = o;
    } else {
        const int kh = head - 40;
        *(f16x8*)&tl[wv][s_loc][ch * 8] = v;
        asm volatile("s_waitcnt lgkmcnt(0)" ::: "memory");
        f16x8 cv;
#pragma unroll
        for (int rr = 0; rr < 8; rr++) cv[rr] = tl[wv][rr][lane];
        const int d = lane, dh = d >> 5;
        const int t = s0 >> 5, c = (s0 >> 4) & 1, hv = (s0 >> 3) & 1;
        const int g = dh * 2 + c;
        f16* dst = Vf + (((size_t)(b * 8 + kh) * 256 + t * 4 + g) * 512
                         + ((d & 31) + (hv << 5)) * 8);
        *(f16x8*)dst = cv;
    }
}

// ---- flash attention, causal, GQA, split-KV x2, 2-tile pipelined ------------
// EXACT R10 structure (best measured: attn 69.5us, 104 VGPR, total 186.7us).
// FIXED-SHIFT softmax (scores bounded, p = exp2(s) in f16 normal range).
// Pair loop interleaves two tiles: QKa; expa; QKb; PVa; expb; PVb.

struct AttnPart { f32x16 o0, o1; float l; };

__device__ __forceinline__ void do_exp(const f32x16& st, unsigned* X, float& lrun) {
    float ps0 = 0.0f, ps1 = 0.0f;
#pragma unroll
    for (int j = 0; j < 8; j++) {
        float p0 = __builtin_amdgcn_exp2f(st[2 * j]);
        float p1 = __builtin_amdgcn_exp2f(st[2 * j + 1]);
        ps0 += p0; ps1 += p1;
        X[j] = pk2(p0, p1);
    }
    lrun += ps0 + ps1;
}

__device__ __forceinline__ void do_pv(const f16x8* va, const f16x8* vb,
                                      const unsigned* X, f32x16& o0, f32x16& o1) {
#pragma unroll
    for (int c = 0; c < 2; c++) {
        unsigned a0 = X[4 * c], a1 = X[4 * c + 1], a2 = X[4 * c + 2], a3 = X[4 * c + 3];
        asm volatile("v_permlane32_swap_b32 %0, %1" : "+v"(a0), "+v"(a2));
        asm volatile("v_permlane32_swap_b32 %0, %1" : "+v"(a1), "+v"(a3));
        union { unsigned u[4]; f16x8 v; } pb;
        pb.u[0] = a0; pb.u[1] = a1; pb.u[2] = a2; pb.u[3] = a3;
        o0 = __builtin_amdgcn_mfma_f32_32x32x16_f16(va[c], pb.v, o0, 0, 0, 0);
        o1 = __builtin_amdgcn_mfma_f32_32x32x16_f16(vb[c], pb.v, o1, 0, 0, 0);
    }
}

__device__ __forceinline__ void do_mask(f32x16& st, int lq, int hi) {
#pragma unroll
    for (int r = 0; r < 16; r++) {
        int kvl = (r & 3) + ((r >> 2) << 3) + (hi << 2);
        if (kvl > lq) st[r] = -1e30f;
    }
}

__device__ __forceinline__ AttnPart attn_part(int qb, int par, int lane, int lq, int hi,
        const f16* __restrict__ Qfp, const f16* __restrict__ Kfp,
        const f16* __restrict__ Vfp) {
    f16x8 qf[4];
#pragma unroll
    for (int c = 0; c < 4; c++)
        qf[c] = *(const f16x8*)&Qfp[((size_t)qb * 4 + c) * 512 + lane * 8];

    AttnPart P;
    P.o0 = (f32x16){}; P.o1 = (f32x16){};
    float lrun = 0.0f;

    f16x8 kfa[4], kfb[4], vaa[2], vba[2], vab[2], vbb[2];

    auto LOADK = [&](f16x8* kf, int t) {
#pragma unroll
        for (int c = 0; c < 4; c++)
            kf[c] = *(const f16x8*)&Kfp[((size_t)t * 4 + c) * 512 + lane * 8];
    };
    auto LOADV = [&](f16x8* va, f16x8* vb, int t) {
#pragma unroll
        for (int c = 0; c < 2; c++) {
            va[c] = *(const f16x8*)&Vfp[((size_t)t * 4 + c)     * 512 + lane * 8];
            vb[c] = *(const f16x8*)&Vfp[((size_t)t * 4 + 2 + c) * 512 + lane * 8];
        }
    };

    int kt = par;
    if (kt <= qb)     { LOADK(kfa, kt);     LOADV(vaa, vba, kt); }
    if (kt + 2 <= qb) { LOADK(kfb, kt + 2); LOADV(vab, vbb, kt + 2); }

    while (kt + 2 <= qb) {
        const int nx = kt + 4;
        f32x16 sta = {};
#pragma unroll
        for (int c = 0; c < 4; c++)
            sta = __builtin_amdgcn_mfma_f32_32x32x16_f16(kfa[c], qf[c], sta, 0, 0, 0);
        unsigned Xa[8];
        do_exp(sta, Xa, lrun);                       // tile a is never diagonal

        f32x16 stb = {};
#pragma unroll
        for (int c = 0; c < 4; c++)
            stb = __builtin_amdgcn_mfma_f32_32x32x16_f16(kfb[c], qf[c], stb, 0, 0, 0);
        if (nx <= qb) LOADK(kfa, nx);

        do_pv(vaa, vba, Xa, P.o0, P.o1);
        if (nx <= qb) LOADV(vaa, vba, nx);

        if (kt + 2 == qb) do_mask(stb, lq, hi);
        unsigned Xb[8];
        do_exp(stb, Xb, lrun);
        if (nx + 2 <= qb) LOADK(kfb, nx + 2);

        do_pv(vab, vbb, Xb, P.o0, P.o1);
        if (nx + 2 <= qb) LOADV(vab, vbb, nx + 2);

        kt = nx;
    }
    if (kt <= qb) {          // leftover single tile (possibly diagonal)
        f32x16 st = {};
#pragma unroll
        for (int c = 0; c < 4; c++)
            st = __builtin_amdgcn_mfma_f32_32x32x16_f16(kfa[c], qf[c], st, 0, 0, 0);
        if (kt == qb) do_mask(st, lq, hi);
        unsigned X[8];
        do_exp(st, X, lrun);
        do_pv(vaa, vba, X, P.o0, P.o1);
    }

    P.l = lrun + __shfl_xor(lrun, 32);
    return P;
}

__global__ __launch_bounds__(128) void k_attn(const f16* __restrict__ Qf,
                                              const f16* __restrict__ Kf,
                                              const f16* __restrict__ Vf,
                                              f16* __restrict__ ctx) {
    __shared__ float ldsO[32][65];
    __shared__ float ldsL[32];
    const int tid = threadIdx.x;
    const int par = tid >> 6, lane = tid & 63;
    const int lq = lane & 31, hi = lane >> 5;
    const int bh = blockIdx.y, b = bh >> 5, h = bh & 31, kh = h >> 2;
    const int pj = blockIdx.x;                    // 0..31

    const f16* Qfp = Qf + (size_t)(b * 32 + h) * 131072;
    const f16* Kfp = Kf + (size_t)(b * 8 + kh) * 131072;
    const f16* Vfp = Vf + (size_t)(b * 8 + kh) * 131072;
    f16*       ctxbase = ctx + (size_t)b * 2048 * 2048 + h * 64;

    const int qbs[2] = {pj, 63 - pj};
#pragma unroll
    for (int s = 0; s < 2; s++) {
        const int qb = qbs[s];
        AttnPart P = attn_part(qb, par, lane, lq, hi, Qfp, Kfp, Vfp);

        if (par == 1) {
            if (hi == 0) ldsL[lq] = P.l;
#pragma unroll
            for (int r = 0; r < 16; r++) {
                int d = (r & 3) + ((r >> 2) << 3) + (hi << 2);
                ldsO[lq][d]      = P.o0[r];
                ldsO[lq][d + 32] = P.o1[r];
            }
        }
        __syncthreads();
        if (par == 0) {
            float inv = 1.0f / (P.l + ldsL[lq]);
            unsigned* row = (unsigned*)(ctxbase + (size_t)(qb * 32 + lq) * 2048);
#pragma unroll
            for (int g = 0; g < 4; g++) {
                int d = 8 * g + 4 * hi;
                float c0 = (P.o0[4 * g]     + ldsO[lq][d])     * inv;
                float c1 = (P.o0[4 * g + 1] + ldsO[lq][d + 1]) * inv;
                float c2 = (P.o0[4 * g + 2] + ldsO[lq][d + 2]) * inv;
                float c3 = (P.o0[4 * g + 3] + ldsO[lq][d + 3]) * inv;
                uint2 a; a.x = pk2(c0, c1); a.y = pk2(c2, c3);
                *(uint2*)(row + 2 * hi + 4 * g) = a;
                float e0 = (P.o1[4 * g]     + ldsO[lq][d + 32]) * inv;
                float e1 = (P.o1[4 * g + 1] + ldsO[lq][d + 33]) * inv;
                float e2 = (P.o1[4 * g + 2] + ldsO[lq][d + 34]) * inv;
                float e3 = (P.o1[4 * g + 3] + ldsO[lq][d + 35]) * inv;
                uint2 e; e.x = pk2(e0, e1); e.y = pk2(e2, e3);
                *(uint2*)(row + 16 + 2 * hi + 4 * g) = e;
            }
        }
        __syncthreads();
    }
}

// ---- launcher ---------------------------------------------------------------

extern "C" void kernel_launch(void* const* d_in, const int* in_sizes, int n_in,
                              void* d_out, int out_size, void* d_ws, size_t ws_size,
                              hipStream_t stream) {
    const float* x     = (const float*)d_in[0];
    const float* w_qkv = (const float*)d_in[1];
    const float* w_out = (const float*)d_in[2];
    const float* qg    = (const float*)d_in[3];
    const float* kg    = (const float*)d_in[4];
    float* out = (float*)d_out;
    char* ws = (char*)d_ws;

    float* cosT = (float*)(ws);
    float* sinT = (float*)(ws + 262144);
    f16* Xh     = (f16*)(ws + 524288);
    f16* Wqkvh  = (f16*)(ws + 17301504);
    f16* Wouth  = (f16*)(ws + 29884416);
    f16* QKVh   = (f16*)(ws + 38273024);
    f16* Qfb    = (f16*)(ws + 63438848);    // fragment-major Q (pre-scaled), 16 MB
    f16* Kfb    = (f16*)(ws + 80216064);    // fragment-major K, 4 MB
    f16* Vfb    = (f16*)(ws + 84410368);    // fragment-major V, 4 MB
    f16* Ctxh   = (f16*)(ws + 88604672);

    k_cast_all<<<18688, 256, 0, stream>>>(x, w_qkv, w_out, Xh, Wqkvh, Wouth, cosT, sinT);

    // qkv = x @ w_qkv^T : M=4096, N=3072, K=2048  (256x192 tile, 256 blocks)
    k_gemm256<f16, 3><<<dim3(16, 16), 512, 0, stream>>>(Xh, Wqkvh, QKVh, 4096, 3072, 2048);

    // fragment-major post-process: 24576 waves / 4 per block
    k_qkv_post<<<6144, 256, 0, stream>>>(QKVh, qg, kg, cosT, sinT, Qfb, Kfb, Vfb);

    // attention: 2048 blocks x 1 wave-pair, split-KV x2, 2-tile pipelined
    k_attn<<<dim3(32, 64), 128, 0, stream>>>(Qfb, Kfb, Vfb, Ctxh);

    // out = ctx @ w_out^T : M=4096, N=2048, K=2048  (256x128 tile, 256 blocks)
    k_gemm256<float, 2><<<dim3(16, 16), 512, 0, stream>>>(Ctxh, Wouth, out, 4096, 2048, 2048);
}

// Round 16
// 186.610 us; speedup vs baseline: 1.0233x; 1.0053x over previous
//
#include <hip/hip_runtime.h>

typedef _Float16 f16;
typedef __fp16 fp16x2 __attribute__((ext_vector_type(2)));
typedef _Float16 f16x8 __attribute__((ext_vector_type(8)));
typedef float f32x4 __attribute__((ext_vector_type(4)));
typedef float f32x16 __attribute__((ext_vector_type(16)));

#define AS1 __attribute__((address_space(1)))
#define AS3 __attribute__((address_space(3)))

#define SCALE_L2E 0.18033688011112042f   // 0.125 * log2(e), folded into Q

// ---- helpers ---------------------------------------------------------------

__device__ __forceinline__ void gload16(const void* g, void* l) {
    __builtin_amdgcn_global_load_lds(
        (const AS1 unsigned*)(unsigned long long)g,
        (AS3 unsigned*)(unsigned)(unsigned long long)l,
        16, 0, 0);
}

__device__ __forceinline__ unsigned pk2(float a, float b) {
    union { fp16x2 v; unsigned u; } c;
    c.v = __builtin_amdgcn_cvt_pkrtz(a, b);
    return c.u;
}

#define BAR() do { asm volatile("" ::: "memory"); __builtin_amdgcn_s_barrier(); asm volatile("" ::: "memory"); } while (0)

// ---- fused fp32 -> fp16 casts + RoPE table (one launch) ---------------------

__global__ __launch_bounds__(256) void k_cast_all(const float* __restrict__ x,
                                                  const float* __restrict__ wq,
                                                  const float* __restrict__ wo,
                                                  f16* __restrict__ Xh,
                                                  f16* __restrict__ Wqh,
                                                  f16* __restrict__ Woh,
                                                  float* __restrict__ cosT,
                                                  float* __restrict__ sinT) {
    if (blockIdx.x >= 18432) {   // RoPE table: 256 blocks x 256 thr = 65536
        int idx = (blockIdx.x - 18432) * 256 + threadIdx.x;
        int s = idx >> 5, i = idx & 31;
        float ang = (float)s * exp2f(-(float)i * 0.4152410118609190f);
        cosT[idx] = cosf(ang);
        sinT[idx] = sinf(ang);
        return;
    }
    int i = (blockIdx.x * 256 + threadIdx.x) * 4;
    const float* src; f16* dst;
    if (i < 8388608)        { src = x  + i;            dst = Xh  + i; }
    else if (i < 14680064)  { src = wq + (i - 8388608); dst = Wqh + (i - 8388608); }
    else                    { src = wo + (i - 14680064); dst = Woh + (i - 14680064); }
    float4 v = *(const float4*)src;
    union { f16 h[4]; ushort4 u; } c;
    c.h[0] = (f16)v.x; c.h[1] = (f16)v.y; c.h[2] = (f16)v.z; c.h[3] = (f16)v.w;
    *(ushort4*)dst = c.u;
}

// ---- GEMM, 256 x (64*NU) tile, 8-phase counted-vmcnt schedule --------------

template <typename OutT, int NU>
__global__ __launch_bounds__(512, 2) void k_gemm256(const f16* __restrict__ A,
                                                    const f16* __restrict__ Bt,
                                                    OutT* __restrict__ C,
                                                    int M, int N, int K) {
    constexpr int BUFSZ = 32768 + NU * 8192;
    __shared__ __align__(16) char sm[2 * BUFSZ];
    const int tid = threadIdx.x;
    const int lane = tid & 63, wid = tid >> 6;
    const int wm = wid >> 2, wn = wid & 3;          // 2 x 4 waves
    const int lr = lane & 15, g4 = lane >> 4;

    // XCD-aware swizzle (bijective: nwg % 8 == 0 for all our grids)
    const int gx = gridDim.x;
    const int nwg = gx * gridDim.y;
    int lin = blockIdx.y * gx + blockIdx.x;
    lin = (lin & 7) * (nwg >> 3) + (lin >> 3);
    const int bx = lin % gx, by = lin / gx;
    const int m0 = by * 256, n0 = bx * (64 * NU);
    const int NT = K >> 6;

    const int srow = tid >> 3;                          // 0..63
    const int scol = ((tid & 7) ^ (srow & 7)) * 8;      // halfs (pre-swizzled)
    const f16* gA = A  + (size_t)(m0 + srow) * K + scol;
    const f16* gB = Bt + (size_t)(n0 + srow) * K + scol;

    auto STGA = [&](int t, int h) {
        char* d = sm + (t & 1) * BUFSZ + h * 16384 + tid * 16;
        gload16(gA + (size_t)(h * 128) * K + t * 64,      d);
        gload16(gA + (size_t)(h * 128 + 64) * K + t * 64, d + 8192);
    };
    auto STGB = [&](int t) {
#pragma unroll
        for (int u = 0; u < NU; u++)
            gload16(gB + (size_t)(u * 64) * K + t * 64,
                    sm + (t & 1) * BUFSZ + 32768 + u * 8192 + tid * 16);
    };

    f32x4 acc[8][NU] = {};
    f16x8 bfr[NU];

    STGA(0, 0); STGA(0, 1); STGB(0);
    STGA(1, 0); STGA(1, 1); STGB(1);
    if constexpr (NU == 2) asm volatile("s_waitcnt vmcnt(6)" ::: "memory");
    else                   asm volatile("s_waitcnt vmcnt(7)" ::: "memory");
    BAR();

    for (int t = 0; t < NT; ++t) {
        const int buf = t & 1;
        const char* bA = sm + buf * BUFSZ + wm * 16384;
        const char* bB = sm + buf * BUFSZ + 32768;
        const bool sA = (t >= 1) && (t + 1 < NT);
        const bool sB = (t + 2 < NT);
#pragma unroll
        for (int p = 0; p < 4; ++p) {
            const int kk = p >> 1, mh = p & 1;
            f16x8 afr[4];
            if (mh == 0) {
#pragma unroll
                for (int n = 0; n < NU; n++) {
                    const int r = wn * (16 * NU) + n * 16 + lr;
                    bfr[n] = *(const f16x8*)(bB + ((r * 128 + kk * 64 + g4 * 16) ^ ((r & 7) << 4)));
                }
            }
#pragma unroll
            for (int i = 0; i < 4; i++) {
                const int r = (mh * 4 + i) * 16 + lr;
                afr[i] = *(const f16x8*)(bA + ((r * 128 + kk * 64 + g4 * 16) ^ ((r & 7) << 4)));
            }
            if (p == 0 && sA) STGA(t + 1, 0);
            if (p == 1 && sA) STGA(t + 1, 1);
            if (p == 3 && sB) STGB(t + 2);
            BAR();
            asm volatile("s_waitcnt lgkmcnt(0)" ::: "memory");
            __builtin_amdgcn_s_setprio(1);
#pragma unroll
            for (int i = 0; i < 4; i++)
#pragma unroll
                for (int n = 0; n < NU; n++)
                    acc[mh * 4 + i][n] = __builtin_amdgcn_mfma_f32_16x16x32_f16(afr[i], bfr[n], acc[mh * 4 + i][n], 0, 0, 0);
            __builtin_amdgcn_s_setprio(0);
            if (p == 3 && t + 1 < NT) {
                if (t + 2 < NT) {
                    if constexpr (NU == 2) asm volatile("s_waitcnt vmcnt(2)" ::: "memory");
                    else                   asm volatile("s_waitcnt vmcnt(3)" ::: "memory");
                } else {
                    asm volatile("s_waitcnt vmcnt(0)" ::: "memory");
                }
            }
            BAR();
        }
    }

#pragma unroll
    for (int m = 0; m < 8; m++)
#pragma unroll
        for (int n = 0; n < NU; n++) {
            size_t base = (size_t)(m0 + wm * 128 + m * 16 + g4 * 4) * N + (n0 + wn * (16 * NU) + n * 16 + lr);
#pragma unroll
            for (int j = 0; j < 4; j++)
                C[base + (size_t)j * N] = (OutT)acc[m][n][j];
        }
}

// ---- fused RMSNorm + RoPE + QKV split, FRAGMENT-MAJOR outputs ---------------

__global__ __launch_bounds__(256) void k_qkv_post(const f16* __restrict__ qkv,
                                                  const float* __restrict__ qg,
                                                  const float* __restrict__ kg,
                                                  const float* __restrict__ cosT,
                                                  const float* __restrict__ sinT,
                                                  f16* __restrict__ Qf,
                                                  f16* __restrict__ Kf,
                                                  f16* __restrict__ Vf) {
    __shared__ f16 tl[4][8][72];         // per-wave 8x64 transpose tile (V path)
    const int tid = threadIdx.x, lane = tid & 63, wv = tid >> 6;
    const int gw = blockIdx.x * 4 + wv;             // 0..24575
    const int b = gw / 12288;
    const int r0 = gw - b * 12288;
    const int head = r0 >> 8;                        // 0..47
    const int sblk = r0 & 255;
    const int s0 = sblk * 8;
    const int s_loc = lane >> 3, ch = lane & 7;
    const int s = s0 + s_loc;

    f16x8 v = *(const f16x8*)&qkv[((size_t)b * 2048 + s) * 3072 + head * 64 + ch * 8];

    if (head < 40) {
        float vf[8];
#pragma unroll
        for (int j = 0; j < 8; j++) vf[j] = (float)v[j];
        float ss = 0.f;
#pragma unroll
        for (int j = 0; j < 8; j++) ss += vf[j] * vf[j];
        ss += __shfl_xor(ss, 1); ss += __shfl_xor(ss, 2); ss += __shfl_xor(ss, 4);
        float rinv = rsqrtf(ss * (1.0f / 64.0f) + 1e-6f);
        const float* gam = (head < 32 ? qg : kg) + ch * 8;
        float4 g0 = *(const float4*)gam, g1 = *(const float4*)(gam + 4);
        float gv[8] = {g0.x, g0.y, g0.z, g0.w, g1.x, g1.y, g1.z, g1.w};
        float xn[8], ot[8];
#pragma unroll
        for (int j = 0; j < 8; j++) xn[j] = vf[j] * rinv * gv[j];
#pragma unroll
        for (int j = 0; j < 8; j++) ot[j] = __shfl_xor(xn[j], 4);
        const int i0 = (ch & 3) * 8;
        float4 c0  = *(const float4*)&cosT[(s << 5) + i0];
        float4 c1  = *(const float4*)&cosT[(s << 5) + i0 + 4];
        float4 sn0 = *(const float4*)&sinT[(s << 5) + i0];
        float4 sn1 = *(const float4*)&sinT[(s << 5) + i0 + 4];
        float cs[8] = {c0.x, c0.y, c0.z, c0.w, c1.x, c1.y, c1.z, c1.w};
        float sn[8] = {sn0.x, sn0.y, sn0.z, sn0.w, sn1.x, sn1.y, sn1.z, sn1.w};
        float sgn = (ch < 4) ? -1.0f : 1.0f;
        float ov[8];
#pragma unroll
        for (int j = 0; j < 8; j++) ov[j] = xn[j] * cs[j] + sgn * ot[j] * sn[j];
        if (head < 32) {
#pragma unroll
            for (int j = 0; j < 8; j++) ov[j] *= SCALE_L2E;
        }
        uint4 o;
        o.x = pk2(ov[0], ov[1]); o.y = pk2(ov[2], ov[3]);
        o.z = pk2(ov[4], ov[5]); o.w = pk2(ov[6], ov[7]);
        const int t = s >> 5;
        const int lane2 = (s & 31) + ((ch & 1) << 5);
        const int c = ch >> 1;
        f16* dst = (head < 32)
            ? Qf + (((size_t)(b * 32 + head) * 256 + t * 4 + c) * 512 + lane2 * 8)
            : Kf + (((size_t)(b * 8 + head - 32) * 256 + t * 4 + c) * 512 + lane2 * 8);
        *(uint4*)dst = o;
    } else {
        const int kh = head - 40;
        *(f16x8*)&tl[wv][s_loc][ch * 8] = v;
        asm volatile("s_waitcnt lgkmcnt(0)" ::: "memory");
        f16x8 cv;
#pragma unroll
        for (int rr = 0; rr < 8; rr++) cv[rr] = tl[wv][rr][lane];
        const int d = lane, dh = d >> 5;
        const int t = s0 >> 5, c = (s0 >> 4) & 1, hv = (s0 >> 3) & 1;
        const int g = dh * 2 + c;
        f16* dst = Vf + (((size_t)(b * 8 + kh) * 256 + t * 4 + g) * 512
                         + ((d & 31) + (hv << 5)) * 8);
        *(f16x8*)dst = cv;
    }
}

// ---- flash attention, causal, GQA, split-KV x2, 2-tile pipelined ------------
// R10 structure + EARLY K-prefetch: each K reload is issued immediately after
// the QK MFMA cluster that kills its registers (extends latency cover by the
// following exp/PV phases). V reloads stay right after their PV (optimal).
// FIXED-SHIFT softmax (scores bounded, p = exp2(s) in f16 normal range).

struct AttnPart { f32x16 o0, o1; float l; };

__device__ __forceinline__ void do_exp(const f32x16& st, unsigned* X, float& lrun) {
    float ps0 = 0.0f, ps1 = 0.0f;
#pragma unroll
    for (int j = 0; j < 8; j++) {
        float p0 = __builtin_amdgcn_exp2f(st[2 * j]);
        float p1 = __builtin_amdgcn_exp2f(st[2 * j + 1]);
        ps0 += p0; ps1 += p1;
        X[j] = pk2(p0, p1);
    }
    lrun += ps0 + ps1;
}

__device__ __forceinline__ void do_pv(const f16x8* va, const f16x8* vb,
                                      const unsigned* X, f32x16& o0, f32x16& o1) {
#pragma unroll
    for (int c = 0; c < 2; c++) {
        unsigned a0 = X[4 * c], a1 = X[4 * c + 1], a2 = X[4 * c + 2], a3 = X[4 * c + 3];
        asm volatile("v_permlane32_swap_b32 %0, %1" : "+v"(a0), "+v"(a2));
        asm volatile("v_permlane32_swap_b32 %0, %1" : "+v"(a1), "+v"(a3));
        union { unsigned u[4]; f16x8 v; } pb;
        pb.u[0] = a0; pb.u[1] = a1; pb.u[2] = a2; pb.u[3] = a3;
        o0 = __builtin_amdgcn_mfma_f32_32x32x16_f16(va[c], pb.v, o0, 0, 0, 0);
        o1 = __builtin_amdgcn_mfma_f32_32x32x16_f16(vb[c], pb.v, o1, 0, 0, 0);
    }
}

__device__ __forceinline__ void do_mask(f32x16& st, int lq, int hi) {
#pragma unroll
    for (int r = 0; r < 16; r++) {
        int kvl = (r & 3) + ((r >> 2) << 3) + (hi << 2);
        if (kvl > lq) st[r] = -1e30f;
    }
}

__device__ __forceinline__ AttnPart attn_part(int qb, int par, int lane, int lq, int hi,
        const f16* __restrict__ Qfp, const f16* __restrict__ Kfp,
        const f16* __restrict__ Vfp) {
    f16x8 qf[4];
#pragma unroll
    for (int c = 0; c < 4; c++)
        qf[c] = *(const f16x8*)&Qfp[((size_t)qb * 4 + c) * 512 + lane * 8];

    AttnPart P;
    P.o0 = (f32x16){}; P.o1 = (f32x16){};
    float lrun = 0.0f;

    f16x8 kfa[4], kfb[4], vaa[2], vba[2], vab[2], vbb[2];

    auto LOADK = [&](f16x8* kf, int t) {
#pragma unroll
        for (int c = 0; c < 4; c++)
            kf[c] = *(const f16x8*)&Kfp[((size_t)t * 4 + c) * 512 + lane * 8];
    };
    auto LOADV = [&](f16x8* va, f16x8* vb, int t) {
#pragma unroll
        for (int c = 0; c < 2; c++) {
            va[c] = *(const f16x8*)&Vfp[((size_t)t * 4 + c)     * 512 + lane * 8];
            vb[c] = *(const f16x8*)&Vfp[((size_t)t * 4 + 2 + c) * 512 + lane * 8];
        }
    };

    int kt = par;
    if (kt <= qb)     { LOADK(kfa, kt);     LOADV(vaa, vba, kt); }
    if (kt + 2 <= qb) { LOADK(kfb, kt + 2); LOADV(vab, vbb, kt + 2); }

    while (kt + 2 <= qb) {
        const int nx = kt + 4;
        f32x16 sta = {};
#pragma unroll
        for (int c = 0; c < 4; c++)
            sta = __builtin_amdgcn_mfma_f32_32x32x16_f16(kfa[c], qf[c], sta, 0, 0, 0);
        if (nx <= qb) LOADK(kfa, nx);        // moved up: kfa regs died at issue

        unsigned Xa[8];
        do_exp(sta, Xa, lrun);                       // tile a is never diagonal

        f32x16 stb = {};
#pragma unroll
        for (int c = 0; c < 4; c++)
            stb = __builtin_amdgcn_mfma_f32_32x32x16_f16(kfb[c], qf[c], stb, 0, 0, 0);
        if (nx + 2 <= qb) LOADK(kfb, nx + 2); // moved up: kfb regs died at issue

        do_pv(vaa, vba, Xa, P.o0, P.o1);
        if (nx <= qb) LOADV(vaa, vba, nx);

        if (kt + 2 == qb) do_mask(stb, lq, hi);
        unsigned Xb[8];
        do_exp(stb, Xb, lrun);

        do_pv(vab, vbb, Xb, P.o0, P.o1);
        if (nx + 2 <= qb) LOADV(vab, vbb, nx + 2);

        kt = nx;
    }
    if (kt <= qb) {          // leftover single tile (possibly diagonal)
        f32x16 st = {};
#pragma unroll
        for (int c = 0; c < 4; c++)
            st = __builtin_amdgcn_mfma_f32_32x32x16_f16(kfa[c], qf[c], st, 0, 0, 0);
        if (kt == qb) do_mask(st, lq, hi);
        unsigned X[8];
        do_exp(st, X, lrun);
        do_pv(vaa, vba, X, P.o0, P.o1);
    }

    P.l = lrun + __shfl_xor(lrun, 32);
    return P;
}

__global__ __launch_bounds__(128) void k_attn(const f16* __restrict__ Qf,
                                              const f16* __restrict__ Kf,
                                              const f16* __restrict__ Vf,
                                              f16* __restrict__ ctx) {
    __shared__ float ldsO[32][65];
    __shared__ float ldsL[32];
    const int tid = threadIdx.x;
    const int par = tid >> 6, lane = tid & 63;
    const int lq = lane & 31, hi = lane >> 5;
    const int bh = blockIdx.y, b = bh >> 5, h = bh & 31, kh = h >> 2;
    const int pj = blockIdx.x;                    // 0..31

    const f16* Qfp = Qf + (size_t)(b * 32 + h) * 131072;
    const f16* Kfp = Kf + (size_t)(b * 8 + kh) * 131072;
    const f16* Vfp = Vf + (size_t)(b * 8 + kh) * 131072;
    f16*       ctxbase = ctx + (size_t)b * 2048 * 2048 + h * 64;

    const int qbs[2] = {pj, 63 - pj};
#pragma unroll
    for (int s = 0; s < 2; s++) {
        const int qb = qbs[s];
        AttnPart P = attn_part(qb, par, lane, lq, hi, Qfp, Kfp, Vfp);

        if (par == 1) {
            if (hi == 0) ldsL[lq] = P.l;
#pragma unroll
            for (int r = 0; r < 16; r++) {
                int d = (r & 3) + ((r >> 2) << 3) + (hi << 2);
                ldsO[lq][d]      = P.o0[r];
                ldsO[lq][d + 32] = P.o1[r];
            }
        }
        __syncthreads();
        if (par == 0) {
            float inv = 1.0f / (P.l + ldsL[lq]);
            unsigned* row = (unsigned*)(ctxbase + (size_t)(qb * 32 + lq) * 2048);
#pragma unroll
            for (int g = 0; g < 4; g++) {
                int d = 8 * g + 4 * hi;
                float c0 = (P.o0[4 * g]     + ldsO[lq][d])     * inv;
                float c1 = (P.o0[4 * g + 1] + ldsO[lq][d + 1]) * inv;
                float c2 = (P.o0[4 * g + 2] + ldsO[lq][d + 2]) * inv;
                float c3 = (P.o0[4 * g + 3] + ldsO[lq][d + 3]) * inv;
                uint2 a; a.x = pk2(c0, c1); a.y = pk2(c2, c3);
                *(uint2*)(row + 2 * hi + 4 * g) = a;
                float e0 = (P.o1[4 * g]     + ldsO[lq][d + 32]) * inv;
                float e1 = (P.o1[4 * g + 1] + ldsO[lq][d + 33]) * inv;
                float e2 = (P.o1[4 * g + 2] + ldsO[lq][d + 34]) * inv;
                float e3 = (P.o1[4 * g + 3] + ldsO[lq][d + 35]) * inv;
                uint2 e; e.x = pk2(e0, e1); e.y = pk2(e2, e3);
                *(uint2*)(row + 16 + 2 * hi + 4 * g) = e;
            }
        }
        __syncthreads();
    }
}

// ---- launcher ---------------------------------------------------------------

extern "C" void kernel_launch(void* const* d_in, const int* in_sizes, int n_in,
                              void* d_out, int out_size, void* d_ws, size_t ws_size,
                              hipStream_t stream) {
    const float* x     = (const float*)d_in[0];
    const float* w_qkv = (const float*)d_in[1];
    const float* w_out = (const float*)d_in[2];
    const float* qg    = (const float*)d_in[3];
    const float* kg    = (const float*)d_in[4];
    float* out = (float*)d_out;
    char* ws = (char*)d_ws;

    float* cosT = (float*)(ws);
    float* sinT = (float*)(ws + 262144);
    f16* Xh     = (f16*)(ws + 524288);
    f16* Wqkvh  = (f16*)(ws + 17301504);
    f16* Wouth  = (f16*)(ws + 29884416);
    f16* QKVh   = (f16*)(ws + 38273024);
    f16* Qfb    = (f16*)(ws + 63438848);    // fragment-major Q (pre-scaled), 16 MB
    f16* Kfb    = (f16*)(ws + 80216064);    // fragment-major K, 4 MB
    f16* Vfb    = (f16*)(ws + 84410368);    // fragment-major V, 4 MB
    f16* Ctxh   = (f16*)(ws + 88604672);

    k_cast_all<<<18688, 256, 0, stream>>>(x, w_qkv, w_out, Xh, Wqkvh, Wouth, cosT, sinT);

    // qkv = x @ w_qkv^T : M=4096, N=3072, K=2048  (256x192 tile, 256 blocks)
    k_gemm256<f16, 3><<<dim3(16, 16), 512, 0, stream>>>(Xh, Wqkvh, QKVh, 4096, 3072, 2048);

    // fragment-major post-process: 24576 waves / 4 per block
    k_qkv_post<<<6144, 256, 0, stream>>>(QKVh, qg, kg, cosT, sinT, Qfb, Kfb, Vfb);

    // attention: 2048 blocks x 1 wave-pair, split-KV x2, 2-tile pipelined
    k_attn<<<dim3(32, 64), 128, 0, stream>>>(Qfb, Kfb, Vfb, Ctxh);

    // out = ctx @ w_out^T : M=4096, N=2048, K=2048  (256x128 tile, 256 blocks)
    k_gemm256<float, 2><<<dim3(16, 16), 512, 0, stream>>>(Ctxh, Wouth, out, 4096, 2048, 2048);
}